// Round 3
// baseline (1118.314 us; speedup 1.0000x reference)
//
#include <hip/hip_runtime.h>
#include <hip/hip_bf16.h>
#include <stdint.h>

typedef __bf16 bf16_t;
typedef bf16_t bf16x8 __attribute__((ext_vector_type(8)));
typedef float f32x4 __attribute__((ext_vector_type(4)));

#define MFMA16(a, b, c) __builtin_amdgcn_mfma_f32_16x16x32_bf16(a, b, c, 0, 0, 0)

static constexpr int kNH = 16;
static constexpr float kScale = 0.17677669529663687f;  // 1/sqrt(32)

// ---------------------------------------------------------------------------
// k_prep: fp32 weights -> bf16 transposed (B^T layout for MFMA B-frags),
// fused bias_table[rel_index] + mask -> bmm[wi][h][i][j] fp32
// ---------------------------------------------------------------------------
__global__ __launch_bounds__(256) void k_prep(
    const float* __restrict__ wqkv,   // [512][1536] fp32
    const float* __restrict__ wproj,  // [512][512]  fp32
    const float* __restrict__ btab,   // [169][16]   fp32
    const float* __restrict__ mask,   // [16][49][49] fp32
    const int*   __restrict__ relidx, // [2401]
    bf16_t* __restrict__ wqkvT,       // [1536][512] bf16
    bf16_t* __restrict__ wprojT,      // [512][512]  bf16
    float*  __restrict__ bmm)         // [16][16][49][49] fp32
{
  int idx = blockIdx.x * 256 + threadIdx.x;
  if (idx < 1536 * 512) {
    int n = idx >> 9, k = idx & 511;
    wqkvT[idx] = (bf16_t)wqkv[k * 1536 + n];
  } else if (idx < 1536 * 512 + 512 * 512) {
    int t = idx - 1536 * 512;
    int n = t >> 9, k = t & 511;
    wprojT[t] = (bf16_t)wproj[k * 512 + n];
  } else if (idx < 1536 * 512 + 512 * 512 + 16 * 16 * 49 * 49) {
    int t = idx - (1536 * 512 + 512 * 512);
    int j = t % 49;  int t2 = t / 49;
    int i = t2 % 49; int t3 = t2 / 49;
    int h = t3 & 15; int wi = t3 >> 4;
    bmm[t] = btab[relidx[i * 49 + j] * 16 + h] + mask[(wi * 49 + i) * 49 + j];
  }
}

// ---------------------------------------------------------------------------
// k_attn: one block per (window, head). 384 threads = 6 waves.
// Phase A: qkv = x_win[49,512] @ Wslice[512,96] via MFMA (wave = one N-unit)
// Phase B: S = q~ k^T (+bias+mask), softmax (shfl width-16 reductions)
// Phase D: O = P V -> attn_out[token, C] (bf16 scratch)
// ---------------------------------------------------------------------------
__global__ __launch_bounds__(384) void k_attn(
    const float*  __restrict__ x,      // [128][28][28][512] fp32
    const bf16_t* __restrict__ wqkvT,  // [1536][512] bf16
    const float*  __restrict__ bqkv,   // [1536] fp32
    const float*  __restrict__ bmmG,   // [16][16][49][49] fp32
    bf16_t* __restrict__ attn)         // [100352][512] bf16
{
  const int h  = blockIdx.x;                 // head
  const int w  = blockIdx.y;                 // window (b*16 + wi)
  const int b  = w >> 4, wi = w & 15;
  const int hw = wi >> 2, ww = wi & 3;
  const int tid  = threadIdx.x;
  const int wv   = tid >> 6, lane = tid & 63;
  const int quad = lane >> 4, l16 = lane & 15;

  // xs: x-window K-chunk [64 rows][136] bf16 (stride 272B: 2-way free)
  // ps (P matrix, stride 72) aliases xs after phase A (xs dead by then).
  __shared__ alignas(16) bf16_t xs[64 * 136];
  __shared__ alignas(16) bf16_t qs[64 * 40];
  __shared__ alignas(16) bf16_t ks[64 * 40];
  __shared__ alignas(16) bf16_t vts[32 * 72];   // V transposed [d][token]
  bf16_t* ps = xs;                              // [64][72]

  const int mat = wv >> 1;                   // 0=q 1=k 2=v
  const int nt  = wv & 1;                    // 16-col half within the head
  const int nglob = mat * 512 + h * 32 + nt * 16 + l16;
  const bf16_t* wbase = wqkvT + nglob * 512;

  const f32x4 zero4 = {0.f, 0.f, 0.f, 0.f};
  f32x4 acc[4] = {zero4, zero4, zero4, zero4};

  const int xoff0 = ((b * 28 + hw * 7) * 28 + ww * 7) * 512;

  // zero-fill xs rows 49..63 ONCE (read by MFMA A-frags, never staged)
  {
    const uint4 z4 = {0u, 0u, 0u, 0u};
    for (int u = tid; u < 15 * 16; u += 384) {
      int row = 49 + (u >> 4), cg = u & 15;
      *(uint4*)&xs[row * 136 + cg * 8] = z4;
    }
  }

  for (int kc = 0; kc < 4; ++kc) {           // K chunks of 128
    for (int u = tid; u < 49 * 16; u += 384) {
      int row = u >> 4, cg = u & 15;
      int i = row / 7, j = row - i * 7;
      const float* src = x + xoff0 + (i * 28 + j) * 512 + kc * 128 + cg * 8;
      float4 f0 = *(const float4*)src;
      float4 f1 = *(const float4*)(src + 4);
      bf16x8 v;
      v[0] = (bf16_t)f0.x; v[1] = (bf16_t)f0.y; v[2] = (bf16_t)f0.z; v[3] = (bf16_t)f0.w;
      v[4] = (bf16_t)f1.x; v[5] = (bf16_t)f1.y; v[6] = (bf16_t)f1.z; v[7] = (bf16_t)f1.w;
      *(bf16x8*)&xs[row * 136 + cg * 8] = v;
    }
    __syncthreads();
#pragma unroll
    for (int kk = 0; kk < 4; ++kk) {
      bf16x8 bfr = *(const bf16x8*)(wbase + kc * 128 + kk * 32 + quad * 8);
#pragma unroll
      for (int mt = 0; mt < 4; ++mt) {
        bf16x8 afr = *(const bf16x8*)&xs[(mt * 16 + l16) * 136 + kk * 32 + quad * 8];
        acc[mt] = MFMA16(afr, bfr, acc[mt]);
      }
    }
    __syncthreads();
  }

  // epilogue A: +bias, q scaled, into frag-layout LDS
  {
    float bias = bqkv[nglob];
#pragma unroll
    for (int mt = 0; mt < 4; ++mt) {
#pragma unroll
      for (int r = 0; r < 4; ++r) {
        int row = mt * 16 + quad * 4 + r;
        float v = acc[mt][r] + bias;
        if (mat == 0)      qs[row * 40 + nt * 16 + l16] = (bf16_t)(v * kScale);
        else if (mat == 1) ks[row * 40 + nt * 16 + l16] = (bf16_t)v;
        else               vts[(nt * 16 + l16) * 72 + row] = (bf16_t)(row < 49 ? v : 0.f);
      }
    }
  }
  __syncthreads();

  if (wv < 4) {                              // waves 0..3: one 16-row M-tile each
    // ---- S = q~ @ k^T ----
    f32x4 sacc[4] = {zero4, zero4, zero4, zero4};
    bf16x8 qa = *(const bf16x8*)&qs[(wv * 16 + l16) * 40 + quad * 8];
#pragma unroll
    for (int n2 = 0; n2 < 4; ++n2) {
      bf16x8 kb = *(const bf16x8*)&ks[(n2 * 16 + l16) * 40 + quad * 8];
      sacc[n2] = MFMA16(qa, kb, sacc[n2]);
    }
    // ---- bias + mask + softmax ----
    const float* bmm = bmmG + (wi * 16 + h) * 2401;
#pragma unroll
    for (int r = 0; r < 4; ++r) {
      int i = wv * 16 + quad * 4 + r;
      bool iv = (i < 49);
      float sv[4];
      float mx = -3e38f;
#pragma unroll
      for (int n2 = 0; n2 < 4; ++n2) {
        int j = n2 * 16 + l16;
        bool valid = iv && (j < 49);
        sv[n2] = valid ? (sacc[n2][r] + bmm[i * 49 + j]) : -3e38f;
        mx = fmaxf(mx, sv[n2]);
      }
#pragma unroll
      for (int off = 1; off < 16; off <<= 1)
        mx = fmaxf(mx, __shfl_xor(mx, off, 16));
      float e[4], sum = 0.f;
#pragma unroll
      for (int n2 = 0; n2 < 4; ++n2) {
        e[n2] = (sv[n2] > -2e38f) ? __expf(sv[n2] - mx) : 0.f;
        sum += e[n2];
      }
#pragma unroll
      for (int off = 1; off < 16; off <<= 1)
        sum += __shfl_xor(sum, off, 16);
      float rinv = (sum > 0.f) ? (1.f / sum) : 0.f;   // padded rows: no 0*inf
#pragma unroll
      for (int n2 = 0; n2 < 4; ++n2)
        ps[i * 72 + n2 * 16 + l16] = (bf16_t)(e[n2] * rinv);   // j>=49 -> 0
    }
  }
  __syncthreads();   // P fully in LDS before PV reads it

  if (wv < 4) {
    // ---- O = P @ V ----
    f32x4 oacc[2] = {zero4, zero4};
#pragma unroll
    for (int kk = 0; kk < 2; ++kk) {
      bf16x8 pa = *(const bf16x8*)&ps[(wv * 16 + l16) * 72 + kk * 32 + quad * 8];
#pragma unroll
      for (int nv = 0; nv < 2; ++nv) {
        bf16x8 vb = *(const bf16x8*)&vts[(nv * 16 + l16) * 72 + kk * 32 + quad * 8];
        oacc[nv] = MFMA16(pa, vb, oacc[nv]);
      }
    }
#pragma unroll
    for (int r = 0; r < 4; ++r) {
      int l = wv * 16 + quad * 4 + r;
      if (l < 49) {
        int i = l / 7, j = l - i * 7;
        int orow = xoff0 + (i * 28 + j) * 512;
#pragma unroll
        for (int nv = 0; nv < 2; ++nv)
          attn[orow + h * 32 + nv * 16 + l16] = (bf16_t)oacc[nv][r];
      }
    }
  }
}

// ---------------------------------------------------------------------------
// k_proj: out[100352,512] = attn(bf16) @ w_projT(bf16) + b_proj -> fp32 out
// ---------------------------------------------------------------------------
__global__ __launch_bounds__(256) void k_proj(
    const bf16_t* __restrict__ A,     // [100352][512] bf16 scratch
    const bf16_t* __restrict__ BT,    // [512][512]  bf16 w_proj^T
    const float*  __restrict__ bias,  // [512] fp32
    float* __restrict__ out)          // [100352][512] fp32
{
  __shared__ alignas(16) bf16_t As[128 * 72];
  __shared__ alignas(16) bf16_t Bs[128 * 72];
  const int tid  = threadIdx.x;
  const int wv   = tid >> 6, lane = tid & 63;
  const int quad = lane >> 4, l16 = lane & 15;
  const int m0 = blockIdx.x * 128, n0 = blockIdx.y * 128;
  const int wr = (wv >> 1) * 64, wc = (wv & 1) * 64;

  const f32x4 zero4 = {0.f, 0.f, 0.f, 0.f};
  f32x4 acc[4][4];
#pragma unroll
  for (int a1 = 0; a1 < 4; ++a1)
#pragma unroll
    for (int a2 = 0; a2 < 4; ++a2) acc[a1][a2] = zero4;

  for (int kt = 0; kt < 8; ++kt) {
    const int k0 = kt * 64;
    for (int u = tid; u < 1024; u += 256) {
      int row = u >> 3, cg = u & 7;
      *(uint4*)&As[row * 72 + cg * 8] = *(const uint4*)(A + (m0 + row) * 512 + k0 + cg * 8);
      *(uint4*)&Bs[row * 72 + cg * 8] = *(const uint4*)(BT + (n0 + row) * 512 + k0 + cg * 8);
    }
    __syncthreads();
#pragma unroll
    for (int kk = 0; kk < 2; ++kk) {
      bf16x8 a[4], bfr[4];
#pragma unroll
      for (int mt = 0; mt < 4; ++mt)
        a[mt] = *(const bf16x8*)&As[(wr + mt * 16 + l16) * 72 + kk * 32 + quad * 8];
#pragma unroll
      for (int n2 = 0; n2 < 4; ++n2)
        bfr[n2] = *(const bf16x8*)&Bs[(wc + n2 * 16 + l16) * 72 + kk * 32 + quad * 8];
#pragma unroll
      for (int mt = 0; mt < 4; ++mt)
#pragma unroll
        for (int n2 = 0; n2 < 4; ++n2)
          acc[mt][n2] = MFMA16(a[mt], bfr[n2], acc[mt][n2]);
    }
    __syncthreads();
  }
#pragma unroll
  for (int n2 = 0; n2 < 4; ++n2) {
    int col = n0 + wc + n2 * 16 + l16;
    float bv = bias[col];
#pragma unroll
    for (int mt = 0; mt < 4; ++mt) {
#pragma unroll
      for (int r = 0; r < 4; ++r) {
        int row = m0 + wr + mt * 16 + quad * 4 + r;
        out[row * 512 + col] = acc[mt][n2][r] + bv;
      }
    }
  }
}

// ---------------------------------------------------------------------------
extern "C" void kernel_launch(void* const* d_in, const int* in_sizes, int n_in,
                              void* d_out, int out_size, void* d_ws, size_t ws_size,
                              hipStream_t stream) {
  const float* x     = (const float*)d_in[0];
  const float* mask  = (const float*)d_in[1];
  const float* wqkv  = (const float*)d_in[2];
  const float* bqkv  = (const float*)d_in[3];
  const float* btab  = (const float*)d_in[4];
  const float* wproj = (const float*)d_in[5];
  const float* bproj = (const float*)d_in[6];
  const int*   relix = (const int*)d_in[7];
  float* out = (float*)d_out;

  char* ws = (char*)d_ws;
  bf16_t* wqkvT  = (bf16_t*)(ws);                 // 1,572,864 B
  bf16_t* wprojT = (bf16_t*)(ws + 1572864);       //   524,288 B
  float*  bmm    = (float*)(ws + 2097152);        // 2,458,624 B
  bf16_t* attn   = (bf16_t*)(ws + 4555776);       // 102,760,448 B

  k_prep<<<6497, 256, 0, stream>>>(wqkv, wproj, btab, mask, relix, wqkvT, wprojT, bmm);
  k_attn<<<dim3(kNH, 2048), 384, 0, stream>>>(x, wqkvT, bqkv, bmm, attn);
  k_proj<<<dim3(784, 4), 256, 0, stream>>>(attn, wprojT, bproj, out);
}